// Round 9
// baseline (1556.949 us; speedup 1.0000x reference)
//
#include <hip/hip_runtime.h>
#include <hip/hip_bf16.h>

#define KDIM 512
#define NBLK 512
#define NTHR 256
#define GST (NBLK * NTHR)

typedef _Float16 f16x8 __attribute__((ext_vector_type(8)));
typedef float f32x4 __attribute__((ext_vector_type(4)));
typedef unsigned short u16x8 __attribute__((ext_vector_type(8)));

static __device__ __forceinline__ unsigned short f2h(float v) {
    _Float16 h = (_Float16)v;
    return *reinterpret_cast<unsigned short*>(&h);
}
static __device__ __forceinline__ float h2f(unsigned short u) {
    _Float16 h = *reinterpret_cast<_Float16*>(&u);
    return (float)h;
}

struct MegaArgs {
    const float* x;
    const int* src;
    const int* dst;
    const float* w[6];        // wl0,wr0,wl1,wr1,wl2,wr2
    const float* wout;
    const float* bl[3];
    const float* bout;
    float* out;
    unsigned* bar;            // [0]=cnt [1]=gen  (memset to 0 on host before launch)
    int* partial;             // [NBLK]
    int* deg;
    int* off;                 // [N+1]
    int* csr;                 // [E]
    unsigned short* xh;       // fp16 [N][512]
    unsigned short* ah;       // fp16 [N][512]
    unsigned short* P;        // fp16 [N][1024]
    unsigned short* WT[3];    // fp16 [1024][512]
    unsigned short* WoT;      // fp16 [O][512]
    int N, E, O;
};

// device-scope generation barrier (same mechanism as hipCG grid.sync):
// all NBLK blocks are co-resident by construction (24KB LDS, <=128 VGPR -> 2 blocks/CU).
__device__ __forceinline__ void gridBarrier(unsigned* bar) {
    __syncthreads();
    if (threadIdx.x == 0) {
        __threadfence();   // release our writes (L2 wb for cross-XCD)
        unsigned g = __hip_atomic_load(&bar[1], __ATOMIC_ACQUIRE, __HIP_MEMORY_SCOPE_AGENT);
        unsigned old = __hip_atomic_fetch_add(&bar[0], 1u, __ATOMIC_ACQ_REL, __HIP_MEMORY_SCOPE_AGENT);
        if (old == NBLK - 1) {
            __hip_atomic_store(&bar[0], 0u, __ATOMIC_RELAXED, __HIP_MEMORY_SCOPE_AGENT);
            __hip_atomic_store(&bar[1], g + 1u, __ATOMIC_RELEASE, __HIP_MEMORY_SCOPE_AGENT);
        } else {
            while (__hip_atomic_load(&bar[1], __ATOMIC_ACQUIRE, __HIP_MEMORY_SCOPE_AGENT) == g)
                __builtin_amdgcn_s_sleep(2);
        }
        __threadfence();   // acquire remote writes
    }
    __syncthreads();
}

// ---- fp16 MFMA GEMM tile, K=512, LDS XOR-swizzled via pre-swizzled source ----
template<int BM, int BN>
__device__ __forceinline__ void gemm_tile(
    const unsigned short* __restrict__ A, const unsigned short* __restrict__ B,
    const float* __restrict__ bias, float* __restrict__ outF,
    unsigned short* __restrict__ outB, int M, int ldo,
    int rowBase, int colBase, unsigned short* As, unsigned short* Bs) {
    constexpr int FM = BM / 32;
    constexpr int FN = BN / 32;
    int tid = threadIdx.x;
    int lane = tid & 63;
    int wid = tid >> 6;
    int wm = (wid >> 1) * (BM / 2);
    int wn = (wid & 1) * (BN / 2);

    f32x4 acc[FM][FN] = {};
    int srow = lane >> 3;
    int scol = ((lane & 7) ^ srow) * 8;

    for (int kt = 0; kt < 8; ++kt) {
        int k0 = kt * 64;
#pragma unroll
        for (int s = 0; s < BM / 32; ++s) {
            int r0 = wid * (BM / 4) + s * 8;
            int gr = rowBase + r0 + srow;
            if (gr >= M) gr = M - 1;
            const unsigned short* g = A + (size_t)gr * KDIM + k0 + scol;
            __builtin_amdgcn_global_load_lds(
                (const __attribute__((address_space(1))) unsigned int*)g,
                (__attribute__((address_space(3))) unsigned int*)&As[r0 * 64],
                16, 0, 0);
        }
#pragma unroll
        for (int s = 0; s < BN / 32; ++s) {
            int r0 = wid * (BN / 4) + s * 8;
            const unsigned short* g = B + (size_t)(colBase + r0 + srow) * KDIM + k0 + scol;
            __builtin_amdgcn_global_load_lds(
                (const __attribute__((address_space(1))) unsigned int*)g,
                (__attribute__((address_space(3))) unsigned int*)&Bs[r0 * 64],
                16, 0, 0);
        }
        __syncthreads();

#pragma unroll
        for (int kk = 0; kk < 2; ++kk) {
            f16x8 aF[FM], bF[FN];
#pragma unroll
            for (int m = 0; m < FM; ++m) {
                int rr = wm + m * 16 + (lane & 15);
                int slot = ((kk << 2) + (lane >> 4)) ^ (lane & 7);
                aF[m] = *(const f16x8*)&As[rr * 64 + slot * 8];
            }
#pragma unroll
            for (int n = 0; n < FN; ++n) {
                int rn = wn + n * 16 + (lane & 15);
                int slot = ((kk << 2) + (lane >> 4)) ^ (lane & 7);
                bF[n] = *(const f16x8*)&Bs[rn * 64 + slot * 8];
            }
#pragma unroll
            for (int m = 0; m < FM; ++m)
#pragma unroll
                for (int n = 0; n < FN; ++n)
                    acc[m][n] = __builtin_amdgcn_mfma_f32_16x16x32_f16(aF[m], bF[n], acc[m][n], 0, 0, 0);
        }
        __syncthreads();
    }

#pragma unroll
    for (int n = 0; n < FN; ++n) {
        int col = colBase + wn + n * 16 + (lane & 15);
        float bb = bias ? bias[col] : 0.0f;
#pragma unroll
        for (int m = 0; m < FM; ++m) {
            int row0 = rowBase + wm + m * 16 + (lane >> 4) * 4;
#pragma unroll
            for (int r = 0; r < 4; ++r) {
                int row = row0 + r;
                if (row < M) {
                    float v = acc[m][n][r] + bb;
                    if (outB) outB[(size_t)row * ldo + col] = f2h(v);
                    else      outF[(size_t)row * ldo + col] = v;
                }
            }
        }
    }
}

// ---- column-sliced gather, 8-edge-parallel fp16 lanes (one virtual unit) ----
__device__ __forceinline__ void gather_unit(
    const unsigned short* __restrict__ P, const int* __restrict__ off,
    const int* __restrict__ csr, const float* __restrict__ bias,
    unsigned short* __restrict__ oh, int n, int v) {
    int slice = v & 7;
    int chunk = v >> 3;
    int wv = threadIdx.x >> 6;
    int lane = threadIdx.x & 63;
    int node = chunk * 4 + wv;
    if (node >= n) return;

    int esub = lane >> 3;
    int c8 = slice * 64 + (lane & 7) * 8;

    int beg = off[node], end = off[node + 1];
    float a[8] = {0.f, 0.f, 0.f, 0.f, 0.f, 0.f, 0.f, 0.f};
    int it = beg + esub;
    for (; it + 8 < end; it += 16) {
        int s0 = csr[it];
        int s1 = csr[it + 8];
        u16x8 v0 = *(const u16x8*)(P + (size_t)s0 * 1024 + c8);
        u16x8 v1 = *(const u16x8*)(P + (size_t)s1 * 1024 + c8);
#pragma unroll
        for (int j = 0; j < 8; ++j) a[j] += h2f(v0[j]) + h2f(v1[j]);
    }
    if (it < end) {
        int s0 = csr[it];
        u16x8 v0 = *(const u16x8*)(P + (size_t)s0 * 1024 + c8);
#pragma unroll
        for (int j = 0; j < 8; ++j) a[j] += h2f(v0[j]);
    }
#pragma unroll
    for (int j = 0; j < 8; ++j) {
        a[j] += __shfl_xor(a[j], 8);
        a[j] += __shfl_xor(a[j], 16);
        a[j] += __shfl_xor(a[j], 32);
    }

    if (esub == 0) {
        float inv = 1.0f / fmaxf((float)(end - beg), 1.0f);
        u16x8 p2 = *(const u16x8*)(P + (size_t)node * 1024 + 512 + c8);
        const float4* pb = (const float4*)(bias + c8);
        float4 b0 = pb[0], b1 = pb[1];
        float bbv[8] = {b0.x, b0.y, b0.z, b0.w, b1.x, b1.y, b1.z, b1.w};
        u16x8 h8;
#pragma unroll
        for (int j = 0; j < 8; ++j) {
            float vv = fmaxf(a[j] * inv + h2f(p2[j]) + bbv[j], 0.f);
            h8[j] = f2h(vv);
        }
        *(u16x8*)(oh + (size_t)node * KDIM + c8) = h8;
    }
}

__global__ __launch_bounds__(NTHR) void mega(MegaArgs a) {
    __shared__ unsigned short As[64 * 64];    // 8 KB
    __shared__ unsigned short Bs[128 * 64];   // 16 KB
    int b = blockIdx.x;
    int tid = threadIdx.x;
    int lane = tid & 63, wv = tid >> 6;
    int gtid = b * NTHR + tid;

    // ---- P0: zero deg; x -> fp16; W -> W^T fp16 (tile transposes) ----
    for (int i = gtid; i < a.N; i += GST) a.deg[i] = 0;
    int total8 = a.N * (KDIM / 8);
    for (int i = gtid; i < total8; i += GST) {
        const float4* p = (const float4*)(a.x + (size_t)i * 8);
        float4 v0 = p[0], v1 = p[1];
        u16x8 h;
        h[0] = f2h(v0.x); h[1] = f2h(v0.y); h[2] = f2h(v0.z); h[3] = f2h(v0.w);
        h[4] = f2h(v1.x); h[5] = f2h(v1.y); h[6] = f2h(v1.z); h[7] = f2h(v1.w);
        *(u16x8*)(a.xh + (size_t)i * 8) = h;
    }
    {
        float (*tc)[33] = reinterpret_cast<float(*)[33]>(As);   // 4224 B alias
        int tx = tid & 31, ty = tid >> 5;
        for (int v = b; v < 1600; v += NBLK) {   // 6*256 hidden tiles + 64 wout tiles
            const float* W; unsigned short* T; int k0, n0, ldw;
            if (v < 1536) {
                int li = v >> 8;
                int t16 = v & 255;
                k0 = (t16 >> 4) * 32; n0 = (t16 & 15) * 32;
                W = a.w[li]; ldw = 512;
                T = a.WT[li >> 1] + (size_t)(li & 1) * 512 * KDIM;
            } else {
                int t2 = v - 1536;
                k0 = (t2 >> 2) * 32; n0 = (t2 & 3) * 32;
                W = a.wout; ldw = a.O; T = a.WoT;
            }
            __syncthreads();
#pragma unroll
            for (int j = 0; j < 4; ++j) {
                int r = ty + j * 8;
                tc[r][tx] = W[(size_t)(k0 + r) * ldw + n0 + tx];
            }
            __syncthreads();
#pragma unroll
            for (int j = 0; j < 4; ++j) {
                int rn = ty + j * 8;
                T[(size_t)(n0 + rn) * KDIM + k0 + tx] = f2h(tc[tx][rn]);
            }
        }
    }
    gridBarrier(a.bar);

    // ---- P1: degree histogram ----
    for (int e = gtid; e < a.E; e += GST) atomicAdd(&a.deg[a.dst[e]], 1);
    gridBarrier(a.bar);

    // ---- P2: per-block partial sums of deg ----
    int CHUNK = (a.N + NBLK - 1) / NBLK;   // 20
    {
        int base = b * CHUNK;
        int v = 0;
        if (tid < CHUNK && base + tid < a.N) v = a.deg[base + tid];
        if (wv == 0) {
            v += __shfl_down(v, 16); v += __shfl_down(v, 8);
            v += __shfl_down(v, 4);  v += __shfl_down(v, 2);
            v += __shfl_down(v, 1);
            if (lane == 0) a.partial[b] = v;
        }
    }
    gridBarrier(a.bar);

    // ---- P3: each block computes its base and writes its off slice ----
    if (tid == 0) {
        int base = 0;
        for (int j = 0; j < b; ++j) base += a.partial[j];
        int lo = b * CHUNK;
        int hi = min(lo + CHUNK, a.N);
        int s = base;
        for (int k = lo; k < hi; ++k) { a.off[k] = s; s += a.deg[k]; }
        if (a.N >= lo && a.N < lo + CHUNK) a.off[a.N] = s;
    }
    gridBarrier(a.bar);

    // ---- P4: fill CSR (deg doubles as down-counting cursor) ----
    for (int e = gtid; e < a.E; e += GST) {
        int d = a.dst[e];
        int p = atomicSub(&a.deg[d], 1);
        a.csr[a.off[d] + p - 1] = a.src[e];
    }
    gridBarrier(a.bar);

    // ---- layers ----
    const unsigned short* inH[4] = {a.xh, a.ah, a.xh, a.ah};
#pragma unroll
    for (int L = 0; L < 3; ++L) {
        // GEMM: 1256 virtual tiles, XCD-chunked (v&7 == b&7 constant per block)
        for (int v = b; v < 1256; v += NBLK) {
            int tile = (v & 7) * 157 + (v >> 3);      // m204 map, 1256 % 8 == 0
            int rowBase = (tile >> 3) * 64;           // NBY = 8
            int colBase = (tile & 7) * 128;
            gemm_tile<64, 128>(inH[L], a.WT[L], nullptr, nullptr, a.P,
                               a.N, 1024, rowBase, colBase, As, Bs);
        }
        gridBarrier(a.bar);
        // gather: 20000 virtual units, slice pinned to b&7
        unsigned short* oh = (unsigned short*)inH[L + 1];
        for (int v = b; v < 20000; v += NBLK)
            gather_unit(a.P, a.off, a.csr, a.bl[L], oh, a.N, v);
        gridBarrier(a.bar);
    }

    // ---- output projection: 314 tiles (BM=64, BN=64, NBY=2) ----
    for (int v = b; v < 314; v += NBLK) {
        int q = 314 >> 3, rr = 314 & 7;
        int xcd = v & 7;
        int tile = (xcd < rr ? xcd * (q + 1) : rr * (q + 1) + (xcd - rr) * q) + (v >> 3);
        int rowBase = (tile >> 1) * 64;
        int colBase = (tile & 1) * 64;
        gemm_tile<64, 64>(inH[3], a.WoT, a.bout, a.out, nullptr,
                          a.N, a.O, rowBase, colBase, As, Bs);
    }
}

// ---------------- launch ----------------

extern "C" void kernel_launch(void* const* d_in, const int* in_sizes, int n_in,
                              void* d_out, int out_size, void* d_ws, size_t ws_size,
                              hipStream_t stream) {
    MegaArgs a;
    a.x    = (const float*)d_in[0];
    const int* ei = (const int*)d_in[1];
    a.w[0] = (const float*)d_in[2];   // wl0
    a.bl[0]= (const float*)d_in[3];
    a.w[1] = (const float*)d_in[4];   // wr0
    a.w[2] = (const float*)d_in[5];   // wl1
    a.bl[1]= (const float*)d_in[6];
    a.w[3] = (const float*)d_in[7];   // wr1
    a.w[4] = (const float*)d_in[8];   // wl2
    a.bl[2]= (const float*)d_in[9];
    a.w[5] = (const float*)d_in[10];  // wr2
    a.wout = (const float*)d_in[11];
    a.bout = (const float*)d_in[12];
    a.out  = (float*)d_out;

    a.N = in_sizes[0] / KDIM;   // 10000
    a.E = in_sizes[1] / 2;      // 160000
    a.O = in_sizes[12];         // 128
    a.src = ei;
    a.dst = ei + a.E;

    char* ws = (char*)d_ws;
    auto align = [](size_t o) { return (o + 255) & ~(size_t)255; };
    size_t o = 0;
    a.bar     = (unsigned*)(ws + o); o = align(o + 256);
    a.partial = (int*)(ws + o);      o = align(o + (size_t)NBLK * 4);
    a.deg     = (int*)(ws + o);      o = align(o + (size_t)a.N * 4);
    a.off     = (int*)(ws + o);      o = align(o + (size_t)(a.N + 1) * 4);
    a.csr     = (int*)(ws + o);      o = align(o + (size_t)a.E * 4);
    size_t planeB = (size_t)a.N * KDIM * 2;
    a.xh = (unsigned short*)(ws + o); o = align(o + planeB);
    a.ah = (unsigned short*)(ws + o); o = align(o + planeB);
    a.P  = (unsigned short*)(ws + o); o = align(o + (size_t)a.N * 1024 * 2);
    for (int i = 0; i < 3; ++i) {
        a.WT[i] = (unsigned short*)(ws + o);
        o = align(o + (size_t)1024 * KDIM * 2);
    }
    a.WoT = (unsigned short*)(ws + o); o = align(o + (size_t)a.O * KDIM * 2);

    hipMemsetAsync(a.bar, 0, 256, stream);   // cnt = gen = 0
    mega<<<NBLK, NTHR, 0, stream>>>(a);
}

// Round 10
// 311.319 us; speedup vs baseline: 5.0011x; 5.0011x over previous
//
#include <hip/hip_runtime.h>
#include <hip/hip_bf16.h>

#define KDIM 512
#define INIT_NBLK 512
#define INIT_GST (INIT_NBLK * 256)

typedef _Float16 f16x8 __attribute__((ext_vector_type(8)));
typedef float f32x4 __attribute__((ext_vector_type(4)));
typedef unsigned short u16x8 __attribute__((ext_vector_type(8)));

static __device__ __forceinline__ unsigned short f2h(float v) {
    _Float16 h = (_Float16)v;
    return *reinterpret_cast<unsigned short*>(&h);
}
static __device__ __forceinline__ float h2f(unsigned short u) {
    _Float16 h = *reinterpret_cast<_Float16*>(&u);
    return (float)h;
}

// ---------------- K1: fused init ----------------
// zero deg; x fp32 -> fp16; all weights fp32 -> W^T fp16 (LDS tile transpose)

struct InitArgs {
    const float* x;
    const float* w[6];        // wl0,wr0,wl1,wr1,wl2,wr2
    const float* wout;
    int* deg;
    unsigned short* xh;
    unsigned short* WT[3];    // [1024][512]
    unsigned short* WoT;      // [O][512]
    int N, O;
};

__global__ __launch_bounds__(256) void init_kernel(InitArgs a) {
    __shared__ float tc[32][33];
    int b = blockIdx.x;
    int tid = threadIdx.x;
    int gtid = b * 256 + tid;

    for (int i = gtid; i < a.N; i += INIT_GST) a.deg[i] = 0;

    int total8 = a.N * (KDIM / 8);
    for (int i = gtid; i < total8; i += INIT_GST) {
        const float4* p = (const float4*)(a.x + (size_t)i * 8);
        float4 v0 = p[0], v1 = p[1];
        u16x8 h;
        h[0] = f2h(v0.x); h[1] = f2h(v0.y); h[2] = f2h(v0.z); h[3] = f2h(v0.w);
        h[4] = f2h(v1.x); h[5] = f2h(v1.y); h[6] = f2h(v1.z); h[7] = f2h(v1.w);
        *(u16x8*)(a.xh + (size_t)i * 8) = h;
    }

    int tx = tid & 31, ty = tid >> 5;
    for (int v = b; v < 1600; v += INIT_NBLK) {   // 6*256 hidden tiles + 64 wout tiles
        const float* W; unsigned short* T; int k0, n0, ldw;
        if (v < 1536) {
            int li = v >> 8;
            int t16 = v & 255;
            k0 = (t16 >> 4) * 32; n0 = (t16 & 15) * 32;
            W = a.w[li]; ldw = 512;
            T = a.WT[li >> 1] + (size_t)(li & 1) * 512 * KDIM;
        } else {
            int t2 = v - 1536;
            k0 = (t2 >> 2) * 32; n0 = (t2 & 3) * 32;
            W = a.wout; ldw = a.O; T = a.WoT;
        }
        __syncthreads();
#pragma unroll
        for (int j = 0; j < 4; ++j) {
            int r = ty + j * 8;
            tc[r][tx] = W[(size_t)(k0 + r) * ldw + n0 + tx];
        }
        __syncthreads();
#pragma unroll
        for (int j = 0; j < 4; ++j) {
            int rn = ty + j * 8;
            T[(size_t)(n0 + rn) * KDIM + k0 + tx] = f2h(tc[tx][rn]);
        }
    }
}

// ---------------- CSR build ----------------

__global__ void deg_kernel(const int* __restrict__ dst, int* __restrict__ deg, int E) {
    int e = blockIdx.x * blockDim.x + threadIdx.x;
    if (e < E) atomicAdd(&deg[dst[e]], 1);
}

__global__ void scan_kernel(const int* __restrict__ deg, int* __restrict__ off, int n) {
    __shared__ int wsum[16];
    __shared__ int carry;
    int tid = threadIdx.x;
    int lane = tid & 63, wv = tid >> 6;
    if (tid == 0) carry = 0;
    __syncthreads();
    for (int start = 0; start < n; start += 1024) {
        int i = start + tid;
        int orig = (i < n) ? deg[i] : 0;
        int v = orig;
#pragma unroll
        for (int d = 1; d < 64; d <<= 1) {
            int t = __shfl_up(v, d, 64);
            if (lane >= d) v += t;
        }
        if (lane == 63) wsum[wv] = v;
        __syncthreads();
        int base = carry;
        if (wv == 0 && lane < 16) {
            int s = wsum[lane];
#pragma unroll
            for (int d = 1; d < 16; d <<= 1) {
                int t = __shfl_up(s, d, 64);
                if (lane >= d) s += t;
            }
            wsum[lane] = s;
            if (lane == 15) carry = base + s;
        }
        __syncthreads();
        int wpre = (wv == 0) ? 0 : wsum[wv - 1];
        if (i < n) off[i] = base + wpre + v - orig;   // exclusive
        __syncthreads();
    }
    if (tid == 0) off[n] = carry;
}

// fill CSR; deg doubles as down-counting cursor (ends at 0, unused afterwards)
__global__ void fill_csr(const int* __restrict__ src, const int* __restrict__ dst,
                         const int* __restrict__ off, int* __restrict__ deg,
                         int* __restrict__ csr, int E) {
    int e = blockIdx.x * blockDim.x + threadIdx.x;
    if (e < E) {
        int d = dst[e];
        int p = atomicSub(&deg[d], 1);
        csr[off[d] + p - 1] = src[e];
    }
}

// ---------------- fp16 MFMA GEMM, K = 512 ----------------

template<int BM, int BN, bool OUTBF>
__global__ __launch_bounds__(256) void gemm_mfma(
    const unsigned short* __restrict__ A, const unsigned short* __restrict__ B,
    const float* __restrict__ bias, float* __restrict__ outF,
    unsigned short* __restrict__ outB, int M, int ldo, int NBY, int relu) {
    constexpr int FM = BM / 32;
    constexpr int FN = BN / 32;
    __shared__ unsigned short As[BM * 64];
    __shared__ unsigned short Bs[BN * 64];

    int tid = threadIdx.x;
    int lane = tid & 63;
    int wid = tid >> 6;

    // bijective XCD chunk map (m204)
    int nwg = gridDim.x;
    int q = nwg >> 3, rres = nwg & 7;
    int xcd = blockIdx.x & 7;
    int tile = (xcd < rres ? xcd * (q + 1) : rres * (q + 1) + (xcd - rres) * q)
             + (blockIdx.x >> 3);
    int rowBase = (tile / NBY) * BM;
    int colBase = (tile % NBY) * BN;

    int wm = (wid >> 1) * (BM / 2);
    int wn = (wid & 1) * (BN / 2);

    f32x4 acc[FM][FN] = {};

    int srow = lane >> 3;                       // 0..7
    int scol = ((lane & 7) ^ srow) * 8;         // pre-swizzled source chunk

    for (int kt = 0; kt < 8; ++kt) {            // 8 x 64 = K 512
        int k0 = kt * 64;

#pragma unroll
        for (int s = 0; s < BM / 32; ++s) {
            int r0 = wid * (BM / 4) + s * 8;
            int gr = rowBase + r0 + srow;
            if (gr >= M) gr = M - 1;
            const unsigned short* g = A + (size_t)gr * KDIM + k0 + scol;
            __builtin_amdgcn_global_load_lds(
                (const __attribute__((address_space(1))) unsigned int*)g,
                (__attribute__((address_space(3))) unsigned int*)&As[r0 * 64],
                16, 0, 0);
        }
#pragma unroll
        for (int s = 0; s < BN / 32; ++s) {
            int r0 = wid * (BN / 4) + s * 8;
            const unsigned short* g = B + (size_t)(colBase + r0 + srow) * KDIM + k0 + scol;
            __builtin_amdgcn_global_load_lds(
                (const __attribute__((address_space(1))) unsigned int*)g,
                (__attribute__((address_space(3))) unsigned int*)&Bs[r0 * 64],
                16, 0, 0);
        }
        __syncthreads();

#pragma unroll
        for (int kk = 0; kk < 2; ++kk) {
            f16x8 aF[FM], bF[FN];
#pragma unroll
            for (int m = 0; m < FM; ++m) {
                int rr = wm + m * 16 + (lane & 15);
                int slot = ((kk << 2) + (lane >> 4)) ^ (lane & 7);
                aF[m] = *(const f16x8*)&As[rr * 64 + slot * 8];
            }
#pragma unroll
            for (int n = 0; n < FN; ++n) {
                int rn = wn + n * 16 + (lane & 15);
                int slot = ((kk << 2) + (lane >> 4)) ^ (lane & 7);
                bF[n] = *(const f16x8*)&Bs[rn * 64 + slot * 8];
            }
#pragma unroll
            for (int m = 0; m < FM; ++m)
#pragma unroll
                for (int n = 0; n < FN; ++n)
                    acc[m][n] = __builtin_amdgcn_mfma_f32_16x16x32_f16(aF[m], bF[n], acc[m][n], 0, 0, 0);
        }
        __syncthreads();
    }

#pragma unroll
    for (int n = 0; n < FN; ++n) {
        int col = colBase + wn + n * 16 + (lane & 15);
        float bb = bias ? bias[col] : 0.0f;
#pragma unroll
        for (int m = 0; m < FM; ++m) {
            int row0 = rowBase + wm + m * 16 + (lane >> 4) * 4;
#pragma unroll
            for (int r = 0; r < 4; ++r) {
                int row = row0 + r;
                if (row < M) {
                    float v = acc[m][n][r] + bb;
                    if (relu) v = fmaxf(v, 0.f);
                    if (OUTBF) outB[(size_t)row * ldo + col] = f2h(v);
                    else       outF[(size_t)row * ldo + col] = v;
                }
            }
        }
    }
}

// ---------------- column-sliced gather, 8-edge-parallel fp16 lanes ----------------

__global__ __launch_bounds__(256) void gather_slice(
    const unsigned short* __restrict__ P, const int* __restrict__ off,
    const int* __restrict__ csr, const float* __restrict__ bias,
    unsigned short* __restrict__ oh, int n) {
    int slice = blockIdx.x & 7;
    int chunk = blockIdx.x >> 3;
    int wv = threadIdx.x >> 6;
    int lane = threadIdx.x & 63;
    int node = chunk * 4 + wv;
    if (node >= n) return;

    int esub = lane >> 3;                  // 0..7 edge sub-lane
    int c8 = slice * 64 + (lane & 7) * 8;  // absolute col oct base

    int beg = off[node], end = off[node + 1];
    float a[8] = {0.f, 0.f, 0.f, 0.f, 0.f, 0.f, 0.f, 0.f};
    int it = beg + esub;
    for (; it + 8 < end; it += 16) {       // two independent chains
        int s0 = csr[it];
        int s1 = csr[it + 8];
        u16x8 v0 = *(const u16x8*)(P + (size_t)s0 * 1024 + c8);
        u16x8 v1 = *(const u16x8*)(P + (size_t)s1 * 1024 + c8);
#pragma unroll
        for (int j = 0; j < 8; ++j) a[j] += h2f(v0[j]) + h2f(v1[j]);
    }
    if (it < end) {
        int s0 = csr[it];
        u16x8 v0 = *(const u16x8*)(P + (size_t)s0 * 1024 + c8);
#pragma unroll
        for (int j = 0; j < 8; ++j) a[j] += h2f(v0[j]);
    }
#pragma unroll
    for (int j = 0; j < 8; ++j) {
        a[j] += __shfl_xor(a[j], 8);
        a[j] += __shfl_xor(a[j], 16);
        a[j] += __shfl_xor(a[j], 32);
    }

    if (esub == 0) {   // lanes 0..7 finalize + store 16B each
        float inv = 1.0f / fmaxf((float)(end - beg), 1.0f);
        u16x8 p2 = *(const u16x8*)(P + (size_t)node * 1024 + 512 + c8);
        const float4* pb = (const float4*)(bias + c8);
        float4 b0 = pb[0], b1 = pb[1];
        float bbv[8] = {b0.x, b0.y, b0.z, b0.w, b1.x, b1.y, b1.z, b1.w};
        u16x8 h8;
#pragma unroll
        for (int j = 0; j < 8; ++j) {
            float v = fmaxf(a[j] * inv + h2f(p2[j]) + bbv[j], 0.f);
            h8[j] = f2h(v);
        }
        *(u16x8*)(oh + (size_t)node * KDIM + c8) = h8;
    }
}

// ---------------- launch (11 dispatches) ----------------

extern "C" void kernel_launch(void* const* d_in, const int* in_sizes, int n_in,
                              void* d_out, int out_size, void* d_ws, size_t ws_size,
                              hipStream_t stream) {
    const float* x    = (const float*)d_in[0];
    const int*   ei   = (const int*)d_in[1];
    const float* bl0  = (const float*)d_in[3];
    const float* bl1  = (const float*)d_in[6];
    const float* bl2  = (const float*)d_in[9];
    const float* bout = (const float*)d_in[12];

    int N = in_sizes[0] / KDIM;     // 10000 nodes
    int E = in_sizes[1] / 2;        // 160000 edges
    int O = in_sizes[12];           // 128

    const int* src = ei;
    const int* dst = ei + E;

    char* ws = (char*)d_ws;
    auto align = [](size_t o) { return (o + 255) & ~(size_t)255; };
    size_t o = 0;
    int* deg = (int*)(ws + o); o = align(o + (size_t)N * 4);
    int* off = (int*)(ws + o); o = align(o + (size_t)(N + 1) * 4);
    int* csr = (int*)(ws + o); o = align(o + (size_t)E * 4);

    size_t planeB = (size_t)N * KDIM * 2;
    unsigned short* x_h = (unsigned short*)(ws + o); o = align(o + planeB);
    unsigned short* a_h = (unsigned short*)(ws + o); o = align(o + planeB);
    unsigned short* P = (unsigned short*)(ws + o); o = align(o + (size_t)N * 1024 * 2);

    unsigned short* WT[3];
    for (int i = 0; i < 3; ++i) {
        WT[i] = (unsigned short*)(ws + o);
        o = align(o + (size_t)1024 * KDIM * 2);
    }
    unsigned short* WoT = (unsigned short*)(ws + o); o = align(o + (size_t)O * KDIM * 2);

    // K1: fused init (zero deg + x->fp16 + all weight transposes)
    {
        InitArgs a;
        a.x = x;
        a.w[0] = (const float*)d_in[2];   // wl0
        a.w[1] = (const float*)d_in[4];   // wr0
        a.w[2] = (const float*)d_in[5];   // wl1
        a.w[3] = (const float*)d_in[7];   // wr1
        a.w[4] = (const float*)d_in[8];   // wl2
        a.w[5] = (const float*)d_in[10];  // wr2
        a.wout = (const float*)d_in[11];
        a.deg = deg;
        a.xh = x_h;
        for (int i = 0; i < 3; ++i) a.WT[i] = WT[i];
        a.WoT = WoT;
        a.N = N; a.O = O;
        init_kernel<<<INIT_NBLK, 256, 0, stream>>>(a);
    }

    // K2-K4: CSR build
    deg_kernel<<<(E + 255) / 256, 256, 0, stream>>>(dst, deg, E);
    scan_kernel<<<1, 1024, 0, stream>>>(deg, off, N);
    fill_csr<<<(E + 255) / 256, 256, 0, stream>>>(src, dst, off, deg, csr, E);

    int nwgH = ((N + 63) / 64) * 8;            // 64x128 tiles: 157 * 8 = 1256
    int gatherBlocks = ((N + 3) / 4) * 8;      // 2500 chunks * 8 slices = 20000
    const float* bl[3] = {bl0, bl1, bl2};
    unsigned short* inH[4] = {x_h, a_h, x_h, a_h};

    // K5-K10: three layers of (GEMM, gather)
    for (int i = 0; i < 3; ++i) {
        gemm_mfma<64, 128, true><<<nwgH, 256, 0, stream>>>(
            inH[i], WT[i], nullptr, nullptr, P, N, 1024, 8, 0);
        gather_slice<<<gatherBlocks, 256, 0, stream>>>(P, off, csr, bl[i], inH[i + 1], N);
    }

    // K11: output projection [N,512] @ [512,128] + bout, fp32 out
    {
        int nwgO = ((N + 63) / 64) * (O / 64);   // 157 * 2 = 314
        gemm_mfma<64, 64, false><<<nwgO, 256, 0, stream>>>(
            inH[3], WoT, bout, (float*)d_out, nullptr, N, O, O / 64, 0);
    }
}

// Round 11
// 290.128 us; speedup vs baseline: 5.3664x; 1.0730x over previous
//
#include <hip/hip_runtime.h>
#include <hip/hip_bf16.h>

#define KDIM 512
#define INIT_NBLK 512
#define INIT_GST (INIT_NBLK * 256)

typedef _Float16 f16x8 __attribute__((ext_vector_type(8)));
typedef float f32x4 __attribute__((ext_vector_type(4)));
typedef unsigned short u16x8 __attribute__((ext_vector_type(8)));

static __device__ __forceinline__ unsigned short f2h(float v) {
    _Float16 h = (_Float16)v;
    return *reinterpret_cast<unsigned short*>(&h);
}
static __device__ __forceinline__ float h2f(unsigned short u) {
    _Float16 h = *reinterpret_cast<_Float16*>(&u);
    return (float)h;
}

// ---------------- K1: fused init ----------------

struct InitArgs {
    const float* x;
    const float* w[6];        // wl0,wr0,wl1,wr1,wl2,wr2
    const float* wout;
    int* deg;
    unsigned short* xh;
    unsigned short* WT[3];    // [1024][512]
    unsigned short* WoT;      // [O][512]
    int N, O;
};

__global__ __launch_bounds__(256) void init_kernel(InitArgs a) {
    __shared__ float tc[32][33];
    int b = blockIdx.x;
    int tid = threadIdx.x;
    int gtid = b * 256 + tid;

    for (int i = gtid; i < a.N; i += INIT_GST) a.deg[i] = 0;

    int total8 = a.N * (KDIM / 8);
    for (int i = gtid; i < total8; i += INIT_GST) {
        const float4* p = (const float4*)(a.x + (size_t)i * 8);
        float4 v0 = p[0], v1 = p[1];
        u16x8 h;
        h[0] = f2h(v0.x); h[1] = f2h(v0.y); h[2] = f2h(v0.z); h[3] = f2h(v0.w);
        h[4] = f2h(v1.x); h[5] = f2h(v1.y); h[6] = f2h(v1.z); h[7] = f2h(v1.w);
        *(u16x8*)(a.xh + (size_t)i * 8) = h;
    }

    int tx = tid & 31, ty = tid >> 5;
    for (int v = b; v < 1600; v += INIT_NBLK) {
        const float* W; unsigned short* T; int k0, n0, ldw;
        if (v < 1536) {
            int li = v >> 8;
            int t16 = v & 255;
            k0 = (t16 >> 4) * 32; n0 = (t16 & 15) * 32;
            W = a.w[li]; ldw = 512;
            T = a.WT[li >> 1] + (size_t)(li & 1) * 512 * KDIM;
        } else {
            int t2 = v - 1536;
            k0 = (t2 >> 2) * 32; n0 = (t2 & 3) * 32;
            W = a.wout; ldw = a.O; T = a.WoT;
        }
        __syncthreads();
#pragma unroll
        for (int j = 0; j < 4; ++j) {
            int r = ty + j * 8;
            tc[r][tx] = W[(size_t)(k0 + r) * ldw + n0 + tx];
        }
        __syncthreads();
#pragma unroll
        for (int j = 0; j < 4; ++j) {
            int rn = ty + j * 8;
            T[(size_t)(n0 + rn) * KDIM + k0 + tx] = f2h(tc[tx][rn]);
        }
    }
}

// ---------------- CSR build ----------------

__global__ void deg_kernel(const int* __restrict__ dst, int* __restrict__ deg, int E) {
    int e = blockIdx.x * blockDim.x + threadIdx.x;
    if (e < E) atomicAdd(&deg[dst[e]], 1);
}

__global__ void scan_kernel(const int* __restrict__ deg, int* __restrict__ off, int n) {
    __shared__ int wsum[16];
    __shared__ int carry;
    int tid = threadIdx.x;
    int lane = tid & 63, wv = tid >> 6;
    if (tid == 0) carry = 0;
    __syncthreads();
    for (int start = 0; start < n; start += 1024) {
        int i = start + tid;
        int orig = (i < n) ? deg[i] : 0;
        int v = orig;
#pragma unroll
        for (int d = 1; d < 64; d <<= 1) {
            int t = __shfl_up(v, d, 64);
            if (lane >= d) v += t;
        }
        if (lane == 63) wsum[wv] = v;
        __syncthreads();
        int base = carry;
        if (wv == 0 && lane < 16) {
            int s = wsum[lane];
#pragma unroll
            for (int d = 1; d < 16; d <<= 1) {
                int t = __shfl_up(s, d, 64);
                if (lane >= d) s += t;
            }
            wsum[lane] = s;
            if (lane == 15) carry = base + s;
        }
        __syncthreads();
        int wpre = (wv == 0) ? 0 : wsum[wv - 1];
        if (i < n) off[i] = base + wpre + v - orig;   // exclusive
        __syncthreads();
    }
    if (tid == 0) off[n] = carry;
}

__global__ void fill_csr(const int* __restrict__ src, const int* __restrict__ dst,
                         const int* __restrict__ off, int* __restrict__ deg,
                         int* __restrict__ csr, int E) {
    int e = blockIdx.x * blockDim.x + threadIdx.x;
    if (e < E) {
        int d = dst[e];
        int p = atomicSub(&deg[d], 1);
        csr[off[d] + p - 1] = src[e];
    }
}

// ---------------- hidden-layer GEMM: 2 waves, 64x64 wave tile ----------------
// A [M][512] fp16, B = W^T [1024][512] fp16, out P fp16 [M][1024].
// Block tile 64x128, 128 threads. LDS reads per K-step: 32KB (vs 48KB @ 4-wave).

__global__ __launch_bounds__(128) void gemm_h(
    const unsigned short* __restrict__ A, const unsigned short* __restrict__ B,
    unsigned short* __restrict__ outB, int M) {
    __shared__ unsigned short As[64 * 64];    // 8 KB
    __shared__ unsigned short Bs[128 * 64];   // 16 KB

    int tid = threadIdx.x;
    int lane = tid & 63;
    int wid = tid >> 6;                       // 0..1

    int nwg = gridDim.x;                      // 1256, % 8 == 0
    int q = nwg >> 3;
    int tile = (blockIdx.x & 7) * q + (blockIdx.x >> 3);
    int rowBase = (tile >> 3) * 64;           // NBY = 8
    int colBase = (tile & 7) * 128;
    int wn = wid * 64;

    f32x4 acc[4][4] = {};

    int srow = lane >> 3;
    int scol = ((lane & 7) ^ srow) * 8;

    for (int kt = 0; kt < 8; ++kt) {
        int k0 = kt * 64;
#pragma unroll
        for (int s = 0; s < 4; ++s) {         // A: 4 stripes per wave
            int r0 = wid * 32 + s * 8;
            int gr = rowBase + r0 + srow;
            if (gr >= M) gr = M - 1;
            const unsigned short* g = A + (size_t)gr * KDIM + k0 + scol;
            __builtin_amdgcn_global_load_lds(
                (const __attribute__((address_space(1))) unsigned int*)g,
                (__attribute__((address_space(3))) unsigned int*)&As[r0 * 64],
                16, 0, 0);
        }
#pragma unroll
        for (int s = 0; s < 8; ++s) {         // B: 8 stripes per wave
            int r0 = wid * 64 + s * 8;
            const unsigned short* g = B + (size_t)(colBase + r0 + srow) * KDIM + k0 + scol;
            __builtin_amdgcn_global_load_lds(
                (const __attribute__((address_space(1))) unsigned int*)g,
                (__attribute__((address_space(3))) unsigned int*)&Bs[r0 * 64],
                16, 0, 0);
        }
        __syncthreads();

#pragma unroll
        for (int kk = 0; kk < 2; ++kk) {
            int slot = ((kk << 2) + (lane >> 4)) ^ (lane & 7);
            f16x8 aF[4], bF[4];
#pragma unroll
            for (int m = 0; m < 4; ++m)
                aF[m] = *(const f16x8*)&As[(m * 16 + (lane & 15)) * 64 + slot * 8];
#pragma unroll
            for (int n = 0; n < 4; ++n)
                bF[n] = *(const f16x8*)&Bs[(wn + n * 16 + (lane & 15)) * 64 + slot * 8];
#pragma unroll
            for (int m = 0; m < 4; ++m)
#pragma unroll
                for (int n = 0; n < 4; ++n)
                    acc[m][n] = __builtin_amdgcn_mfma_f32_16x16x32_f16(aF[m], bF[n], acc[m][n], 0, 0, 0);
        }
        __syncthreads();
    }

#pragma unroll
    for (int n = 0; n < 4; ++n) {
        int col = colBase + wn + n * 16 + (lane & 15);
#pragma unroll
        for (int m = 0; m < 4; ++m) {
            int row0 = rowBase + m * 16 + (lane >> 4) * 4;
#pragma unroll
            for (int r = 0; r < 4; ++r) {
                int row = row0 + r;
                if (row < M)
                    outB[(size_t)row * 1024 + col] = f2h(acc[m][n][r]);
            }
        }
    }
}

// ---------------- output GEMM (4-wave 64x64, unchanged from r10) ----------------

__global__ __launch_bounds__(256) void gemm_out(
    const unsigned short* __restrict__ A, const unsigned short* __restrict__ B,
    const float* __restrict__ bias, float* __restrict__ outF, int M, int O) {
    constexpr int BM = 64, BN = 64;
    __shared__ unsigned short As[BM * 64];
    __shared__ unsigned short Bs[BN * 64];

    int tid = threadIdx.x;
    int lane = tid & 63;
    int wid = tid >> 6;

    int nwg = gridDim.x;
    int q = nwg >> 3, rres = nwg & 7;
    int xcd = blockIdx.x & 7;
    int tile = (xcd < rres ? xcd * (q + 1) : rres * (q + 1) + (xcd - rres) * q)
             + (blockIdx.x >> 3);
    int rowBase = (tile >> 1) * BM;           // NBY = 2
    int colBase = (tile & 1) * BN;

    int wm = (wid >> 1) * 32;
    int wn = (wid & 1) * 32;

    f32x4 acc[2][2] = {};
    int srow = lane >> 3;
    int scol = ((lane & 7) ^ srow) * 8;

    for (int kt = 0; kt < 8; ++kt) {
        int k0 = kt * 64;
#pragma unroll
        for (int s = 0; s < 2; ++s) {
            int r0 = wid * 16 + s * 8;
            int gr = rowBase + r0 + srow;
            if (gr >= M) gr = M - 1;
            const unsigned short* g = A + (size_t)gr * KDIM + k0 + scol;
            __builtin_amdgcn_global_load_lds(
                (const __attribute__((address_space(1))) unsigned int*)g,
                (__attribute__((address_space(3))) unsigned int*)&As[r0 * 64],
                16, 0, 0);
        }
#pragma unroll
        for (int s = 0; s < 2; ++s) {
            int r0 = wid * 16 + s * 8;
            const unsigned short* g = B + (size_t)(colBase + r0 + srow) * KDIM + k0 + scol;
            __builtin_amdgcn_global_load_lds(
                (const __attribute__((address_space(1))) unsigned int*)g,
                (__attribute__((address_space(3))) unsigned int*)&Bs[r0 * 64],
                16, 0, 0);
        }
        __syncthreads();

#pragma unroll
        for (int kk = 0; kk < 2; ++kk) {
            int slot = ((kk << 2) + (lane >> 4)) ^ (lane & 7);
            f16x8 aF[2], bF[2];
#pragma unroll
            for (int m = 0; m < 2; ++m)
                aF[m] = *(const f16x8*)&As[(wm + m * 16 + (lane & 15)) * 64 + slot * 8];
#pragma unroll
            for (int n = 0; n < 2; ++n)
                bF[n] = *(const f16x8*)&Bs[(wn + n * 16 + (lane & 15)) * 64 + slot * 8];
#pragma unroll
            for (int m = 0; m < 2; ++m)
#pragma unroll
                for (int n = 0; n < 2; ++n)
                    acc[m][n] = __builtin_amdgcn_mfma_f32_16x16x32_f16(aF[m], bF[n], acc[m][n], 0, 0, 0);
        }
        __syncthreads();
    }

#pragma unroll
    for (int n = 0; n < 2; ++n) {
        int col = colBase + wn + n * 16 + (lane & 15);
        float bb = bias[col];
#pragma unroll
        for (int m = 0; m < 2; ++m) {
            int row0 = rowBase + wm + m * 16 + (lane >> 4) * 4;
#pragma unroll
            for (int r = 0; r < 4; ++r) {
                int row = row0 + r;
                if (row < M)
                    outF[(size_t)row * O + col] = acc[m][n][r] + bb;
            }
        }
    }
}

// ---------------- gather: packed-fp16 accumulation, 8-edge chains ----------------

__global__ __launch_bounds__(256) void gather_slice(
    const unsigned short* __restrict__ P, const int* __restrict__ off,
    const int* __restrict__ csr, const float* __restrict__ bias,
    unsigned short* __restrict__ oh, int n) {
    int slice = blockIdx.x & 7;
    int chunk = blockIdx.x >> 3;
    int wv = threadIdx.x >> 6;
    int lane = threadIdx.x & 63;
    int node = chunk * 4 + wv;
    if (node >= n) return;

    int esub = lane >> 3;                  // 0..7 edge sub-lane
    int c8 = slice * 64 + (lane & 7) * 8;  // absolute col oct base

    int beg = off[node], end = off[node + 1];
    f16x8 acc8 = {};
    int it = beg + esub;
    for (; it + 8 < end; it += 16) {       // two independent chains
        int s0 = csr[it];
        int s1 = csr[it + 8];
        f16x8 v0 = *(const f16x8*)(P + (size_t)s0 * 1024 + c8);
        f16x8 v1 = *(const f16x8*)(P + (size_t)s1 * 1024 + c8);
        acc8 += v0 + v1;                   // v_pk_add_f16
    }
    if (it < end) {
        int s0 = csr[it];
        acc8 += *(const f16x8*)(P + (size_t)s0 * 1024 + c8);
    }
    // combine 8 edge groups (lane bits 3,4,5) on packed words
#pragma unroll
    for (int st = 8; st <= 32; st <<= 1) {
        f16x8 other;
        int* op = reinterpret_cast<int*>(&other);
        const int* ap = reinterpret_cast<const int*>(&acc8);
#pragma unroll
        for (int w = 0; w < 4; ++w) op[w] = __shfl_xor(ap[w], st);
        acc8 += other;
    }

    if (esub == 0) {   // lanes 0..7 finalize + store 16B each
        float inv = 1.0f / fmaxf((float)(end - beg), 1.0f);
        u16x8 p2 = *(const u16x8*)(P + (size_t)node * 1024 + 512 + c8);
        const float4* pb = (const float4*)(bias + c8);
        float4 b0 = pb[0], b1 = pb[1];
        float bbv[8] = {b0.x, b0.y, b0.z, b0.w, b1.x, b1.y, b1.z, b1.w};
        u16x8 h8;
#pragma unroll
        for (int j = 0; j < 8; ++j) {
            float v = fmaxf((float)acc8[j] * inv + h2f(p2[j]) + bbv[j], 0.f);
            h8[j] = f2h(v);
        }
        *(u16x8*)(oh + (size_t)node * KDIM + c8) = h8;
    }
}

// ---------------- launch (11 dispatches) ----------------

extern "C" void kernel_launch(void* const* d_in, const int* in_sizes, int n_in,
                              void* d_out, int out_size, void* d_ws, size_t ws_size,
                              hipStream_t stream) {
    const float* x    = (const float*)d_in[0];
    const int*   ei   = (const int*)d_in[1];
    const float* bl0  = (const float*)d_in[3];
    const float* bl1  = (const float*)d_in[6];
    const float* bl2  = (const float*)d_in[9];
    const float* bout = (const float*)d_in[12];

    int N = in_sizes[0] / KDIM;     // 10000 nodes
    int E = in_sizes[1] / 2;        // 160000 edges
    int O = in_sizes[12];           // 128

    const int* src = ei;
    const int* dst = ei + E;

    char* ws = (char*)d_ws;
    auto align = [](size_t o) { return (o + 255) & ~(size_t)255; };
    size_t o = 0;
    int* deg = (int*)(ws + o); o = align(o + (size_t)N * 4);
    int* off = (int*)(ws + o); o = align(o + (size_t)(N + 1) * 4);
    int* csr = (int*)(ws + o); o = align(o + (size_t)E * 4);

    size_t planeB = (size_t)N * KDIM * 2;
    unsigned short* x_h = (unsigned short*)(ws + o); o = align(o + planeB);
    unsigned short* a_h = (unsigned short*)(ws + o); o = align(o + planeB);
    unsigned short* P = (unsigned short*)(ws + o); o = align(o + (size_t)N * 1024 * 2);

    unsigned short* WT[3];
    for (int i = 0; i < 3; ++i) {
        WT[i] = (unsigned short*)(ws + o);
        o = align(o + (size_t)1024 * KDIM * 2);
    }
    unsigned short* WoT = (unsigned short*)(ws + o); o = align(o + (size_t)O * KDIM * 2);

    // K1: fused init
    {
        InitArgs a;
        a.x = x;
        a.w[0] = (const float*)d_in[2];   // wl0
        a.w[1] = (const float*)d_in[4];   // wr0
        a.w[2] = (const float*)d_in[5];   // wl1
        a.w[3] = (const float*)d_in[7];   // wr1
        a.w[4] = (const float*)d_in[8];   // wl2
        a.w[5] = (const float*)d_in[10];  // wr2
        a.wout = (const float*)d_in[11];
        a.deg = deg;
        a.xh = x_h;
        for (int i = 0; i < 3; ++i) a.WT[i] = WT[i];
        a.WoT = WoT;
        a.N = N; a.O = O;
        init_kernel<<<INIT_NBLK, 256, 0, stream>>>(a);
    }

    // K2-K4: CSR build
    deg_kernel<<<(E + 255) / 256, 256, 0, stream>>>(dst, deg, E);
    scan_kernel<<<1, 1024, 0, stream>>>(deg, off, N);
    fill_csr<<<(E + 255) / 256, 256, 0, stream>>>(src, dst, off, deg, csr, E);

    int nwgH = ((N + 63) / 64) * 8;            // 157 * 8 = 1256
    int gatherBlocks = ((N + 3) / 4) * 8;      // 20000
    const float* bl[3] = {bl0, bl1, bl2};
    unsigned short* inH[4] = {x_h, a_h, x_h, a_h};

    // K5-K10: three layers of (GEMM, gather)
    for (int i = 0; i < 3; ++i) {
        gemm_h<<<nwgH, 128, 0, stream>>>(inH[i], WT[i], P, N);
        gather_slice<<<gatherBlocks, 256, 0, stream>>>(P, off, csr, bl[i], inH[i + 1], N);
    }

    // K11: output projection
    {
        int nwgO = ((N + 63) / 64) * (O / 64);   // 314
        gemm_out<<<nwgO, 256, 0, stream>>>(inH[3], WoT, bout, (float*)d_out, N, O);
    }
}